// Round 9
// baseline (239.455 us; speedup 1.0000x reference)
//
#include <hip/hip_runtime.h>
#include <hip/hip_bf16.h>
#include <math.h>

#define BB 64
#define HH 128
#define WW 128
#define EE 256
#define HP (HH*EE)        // 32768
#define H2 64
#define W2 128
#define PL2 (H2*W2)       // 8192
#define H4 32
#define W4 64
#define PL4 (H4*W4)       // 2048

typedef __hip_bfloat16 bf;
typedef unsigned short ushortt;
typedef __attribute__((ext_vector_type(8))) __bf16 b8v;
typedef __attribute__((ext_vector_type(4))) float f4v;

__device__ __forceinline__ float tof(bf v)    { return __bfloat162float(v); }
__device__ __forceinline__ bf    tob(float v) { return __float2bfloat16(v); }
__device__ __forceinline__ unsigned int bfbits(float v) {
    return (unsigned int)__builtin_bit_cast(ushortt, __float2bfloat16(v));
}
__device__ __forceinline__ float b2f(unsigned int u16) {
    unsigned int x = u16 << 16;
    return __builtin_bit_cast(float, x);
}
__device__ __forceinline__ void wred2(float& s, float& q) {
    #pragma unroll
    for (int m = 32; m; m >>= 1) {
        s += __shfl_xor(s, m);
        q += __shfl_xor(q, m);
    }
}

// ---------------------------------------------------------------------------
// K1: fused Fourier features + fc1 GEMM via MFMA. 512 blocks.
// Prologue grid-stride zeroes the stats buffer.
__global__ __launch_bounds__(256) void k_fourier_fc1(
    const float* __restrict__ x, const float* __restrict__ Wf,
    const float* __restrict__ fc1_w, const float* __restrict__ fc1_b,
    bf* __restrict__ xf, float* __restrict__ mb)
{
    __shared__ ushortt sA[64*264];
    __shared__ ushortt sB[64*264];
    int t = threadIdx.x;
    for (int i = blockIdx.x*256 + t; i < 9280; i += 512*256) mb[i] = 0.f;
    int rb = blockIdx.x >> 2, cb = blockIdx.x & 3;
    int row0 = rb*64, col0 = cb*64;
    const float TP = 6.2831853071795864769f;
    for (int it = 0; it < 32; ++it) {       // 8192 = 64 rows x 128 w
        int i = it*256 + t;
        int r = i >> 7, w = i & 127;
        int rg = row0 + r;
        float p = x[(size_t)rg*WW + w] * Wf[(size_t)(rg & (HH-1))*WW + w] * TP;
        sA[r*264 + w]       = (ushortt)bfbits(__sinf(p));
        sA[r*264 + 128 + w] = (ushortt)bfbits(__cosf(p));
    }
    #pragma unroll
    for (int it = 0; it < 16; ++it) {       // B: fp32 -> bf16
        int i = it*256 + t;
        int o = i >> 6, c4 = i & 63;
        float4 w4 = *(const float4*)(fc1_w + (size_t)(col0 + o)*EE + c4*4);
        uint2 pk;
        pk.x = bfbits(w4.x) | (bfbits(w4.y) << 16);
        pk.y = bfbits(w4.z) | (bfbits(w4.w) << 16);
        *(uint2*)&sB[o*264 + c4*4] = pk;
    }
    __syncthreads();
    int lane = t & 63, wid = t >> 6;
    int m = lane & 15, kq = (lane >> 4) * 8;
    f4v acc[4] = {};
    const ushortt* aBase = &sA[(wid*16 + m)*264 + kq];
    #pragma unroll
    for (int k0 = 0; k0 < 8; ++k0) {
        b8v av = *(const b8v*)(aBase + k0*32);
        #pragma unroll
        for (int t4 = 0; t4 < 4; ++t4) {
            b8v bv = *(const b8v*)&sB[(t4*16 + m)*264 + k0*32 + kq];
            acc[t4] = __builtin_amdgcn_mfma_f32_16x16x32_bf16(av, bv, acc[t4], 0, 0, 0);
        }
    }
    int rbase = row0 + wid*16 + (lane >> 4)*4;
    #pragma unroll
    for (int t4 = 0; t4 < 4; ++t4) {
        int col = col0 + t4*16 + m;
        float bias = fc1_b[col];
        #pragma unroll
        for (int r = 0; r < 4; ++r)
            xf[(size_t)(rbase + r)*EE + col] = tob(acc[t4][r] + bias);
    }
}

// ---------------------------------------------------------------------------
// K2: conv1 3x3, 1->6, LDS-staged rows. 8 OUTPUT ROWS/BLOCK (halo 1.25x),
// 1024 blocks, 2 conv passes/thread, fused gn1 stats. XCD-swizzled blockIdx.
__global__ __launch_bounds__(256) void k_conv1(
    const bf* __restrict__ xf, const float* __restrict__ k,
    const float* __restrict__ bias, bf* __restrict__ c1, float* __restrict__ mc1)
{
    __shared__ ushortt sT[10*272];   // 10 rows, data at [8..263], zero halos
    __shared__ float red[4][6][2];
    int t = threadIdx.x;
    int bid = ((blockIdx.x & 7) << 7) | (blockIdx.x >> 3);   // XCD swizzle (1024)
    int ht = bid & 15, b = bid >> 4;
    int h0 = ht*8;
    const bf* src = xf + (size_t)b*HP;
    for (int i = t; i < 320; i += 256) {
        int r = i >> 5, ii = i & 31;
        int gy = h0 - 1 + r;
        uint4 v = {0,0,0,0};
        if (gy >= 0 && gy < HH) v = *(const uint4*)(src + (size_t)gy*EE + ii*8);
        *(uint4*)&sT[r*272 + 8 + ii*8] = v;
    }
    if (t < 20) {
        int r = t >> 1, s = t & 1;
        uint4 z = {0,0,0,0};
        *(uint4*)&sT[r*272 + s*264] = z;
    }
    __syncthreads();
    int wq = (t & 63)*4, hl = t >> 6;
    int lane = t & 63, wid = t >> 6;
    float sA6[6] = {}, qA6[6] = {};
    #pragma unroll
    for (int it = 0; it < 2; ++it) {
        int rb = hl + it*4;
        float v[3][6];
        #pragma unroll
        for (int ky = 0; ky < 3; ++ky)
          #pragma unroll
          for (int j = 0; j < 6; ++j)
            v[ky][j] = b2f((unsigned)sT[(rb+ky)*272 + 7 + wq + j]);
        int h = h0 + rb;
        #pragma unroll
        for (int o = 0; o < 6; ++o) {
            float bv = bias[o];
            float a0=bv, a1=bv, a2=bv, a3=bv;
            #pragma unroll
            for (int ky = 0; ky < 3; ++ky)
              #pragma unroll
              for (int kx = 0; kx < 3; ++kx) {
                float wv = k[o*9 + ky*3 + kx];
                a0 += v[ky][kx+0]*wv;
                a1 += v[ky][kx+1]*wv;
                a2 += v[ky][kx+2]*wv;
                a3 += v[ky][kx+3]*wv;
              }
            uint2 pk;
            pk.x = bfbits(a0) | (bfbits(a1) << 16);
            pk.y = bfbits(a2) | (bfbits(a3) << 16);
            *(uint2*)(c1 + ((size_t)(b*6+o)*HH + h)*EE + wq) = pk;
            sA6[o] += a0+a1+a2+a3;
            qA6[o] += a0*a0+a1*a1+a2*a2+a3*a3;
        }
    }
    #pragma unroll
    for (int o = 0; o < 6; ++o) {
        float s = sA6[o], q = qA6[o];
        wred2(s, q);
        if (lane == 0) { red[wid][o][0] = s; red[wid][o][1] = q; }
    }
    __syncthreads();
    if (t < 6) {
        float S = 0.f, Q = 0.f;
        #pragma unroll
        for (int wv = 0; wv < 4; ++wv) { S += red[wv][t][0]; Q += red[wv][t][1]; }
        atomicAdd(&mc1[((size_t)b*6 + t)*2],     S);
        atomicAdd(&mc1[((size_t)b*6 + t)*2 + 1], Q);
    }
}

// ---------------------------------------------------------------------------
// K5: conv2 3x3, 6->24 via MFMA implicit GEMM, fused gn1+ReLU+pool staging.
// FRAGMENT-DIRECT (magic-div offsets). 4 output rows/block, 1024 blocks.
__global__ __launch_bounds__(256) void k_conv2(
    const bf* __restrict__ c1, const float* __restrict__ mc1,
    const float* __restrict__ g1, const float* __restrict__ be1,
    const float* __restrict__ kw, const float* __restrict__ bias,
    bf* __restrict__ c2, float* __restrict__ mc2)
{
    __shared__ ushortt sW[32*64];
    __shared__ ushortt sP[6*6*136];    // 6 ch x 6 pooled rows x 136 (halo'd)
    __shared__ float ssl[12];
    __shared__ float redS[24], redQ[24];
    int t = threadIdx.x;
    int bid = ((blockIdx.x & 7) << 7) | (blockIdx.x >> 3);   // XCD swizzle (1024)
    int ht = bid & 15, b = bid >> 4;
    int h0 = ht*4;                     // output rows h0..h0+3 (of 64)
    int lane = t & 63, wid = t >> 6;
    int m = lane & 15, q4 = lane >> 4;
    if (t < 24) { redS[t] = 0.f; redQ[t] = 0.f; }
    if (t < 6) {
        float s = mc1[((size_t)b*6 + t)*2], q = mc1[((size_t)b*6 + t)*2 + 1];
        float mean = s * (1.f/HP);
        float var  = q * (1.f/HP) - mean*mean;
        float rstd = rsqrtf(var + 1e-5f);
        float sc = g1[t]*rstd;
        ssl[t*2] = sc; ssl[t*2+1] = be1[t] - mean*sc;
    }
    for (int i = t; i < 1024; i += 256) ((unsigned*)sW)[i] = 0;   // zero W
    if (t < 96) {                      // halo cols (gx=-1,128): 6ch x 6rows x 2
        int c = t >> 4, e = t & 15;
        if (e < 12) {
            int ry = e >> 1, rx = (e & 1) ? 129 : 0;
            sP[c*816 + ry*136 + rx] = 0;
        }
    }
    __syncthreads();
    // stage pooled tile main cols (gn1+ReLU+pool): 6 ch x 6 rows x 128 cols
    #pragma unroll
    for (int j = 0; j < 18; ++j) {
        int i = j*256 + t;             // < 4608 = 6*768
        int c = (i*2731) >> 21;        // i/768 for i<4608
        int rem = i - c*768;
        int ry = rem >> 7, gx = rem & 127;
        int gy = h0 - 1 + ry;
        float v = 0.f;
        if (gy >= 0 && gy < H2) {
            const bf* pp = c1 + ((size_t)(b*6+c)*HH + 2*gy)*EE + 2*gx;
            unsigned r0 = *(const unsigned*)pp;
            unsigned r1 = *(const unsigned*)(pp + EE);
            float sc = ssl[c*2], sh = ssl[c*2+1];
            float e0 = fmaxf(b2f(r0 & 0xffff)*sc+sh, 0.f);
            float e1 = fmaxf(b2f(r0 >> 16)   *sc+sh, 0.f);
            float e2 = fmaxf(b2f(r1 & 0xffff)*sc+sh, 0.f);
            float e3 = fmaxf(b2f(r1 >> 16)   *sc+sh, 0.f);
            v = fmaxf(fmaxf(e0,e1), fmaxf(e2,e3));
        }
        sP[c*816 + ry*136 + gx + 1] = (ushortt)bfbits(v);
    }
    // stage W: kw[o][kk] -> sW[o][swizzled block (kk>>3)^(o&7), elem kk&7]
    #pragma unroll
    for (int j = 0; j < 6; ++j) {
        int i = j*256 + t;             // < 1536 = 24*64
        int o = i >> 6, kk = i & 63;
        if (kk < 54)
            sW[o*64 + ((((kk >> 3) ^ (o & 7)) << 3) | (kk & 7))] =
                (ushortt)bfbits(kw[o*54 + kk]);
    }
    __syncthreads();
    b8v wv[2][2];
    #pragma unroll
    for (int nt = 0; nt < 2; ++nt) {
        int o = nt*16 + m;
        #pragma unroll
        for (int ks = 0; ks < 2; ++ks)
            wv[nt][ks] = *(const b8v*)&sW[o*64 + (((ks*4 + q4) ^ (o & 7)) << 3)];
    }
    // Per-lane A-fragment sP offsets: k = ks*32 + q4*8 + j -> (c,y,x)
    int offA0[8], offA1[8];
    #pragma unroll
    for (int j = 0; j < 8; ++j) {
        int k0 = q4*8 + j;             // 0..31, always valid
        int c = (k0*57) >> 9;
        int r9 = k0 - 9*c;
        int y = (r9*11) >> 5;
        int xk = r9 - 3*y;
        offA0[j] = c*816 + y*136 + xk;
        int k1 = 32 + q4*8 + j;        // 32..63, valid iff < 54
        c = (k1*57) >> 9;
        r9 = k1 - 9*c;
        y = (r9*11) >> 5;
        xk = r9 - 3*y;
        offA1[j] = (k1 < 54) ? (c*816 + y*136 + xk) : -1;
    }
    float sAcc[2] = {0.f, 0.f}, qAcc[2] = {0.f, 0.f};
    #pragma unroll
    for (int pass = 0; pass < 2; ++pass) {
        f4v acc[4][2] = {};
        #pragma unroll
        for (int mt = 0; mt < 4; ++mt) {
            int px = wid*128 + pass*64 + mt*16 + m;     // 0..511
            int badd = (px >> 7)*136 + (px & 127);
            unsigned w0[4], w1[4];
            #pragma unroll
            for (int jj = 0; jj < 4; ++jj) {
                unsigned lo  = sP[offA0[2*jj]   + badd];
                unsigned hi  = sP[offA0[2*jj+1] + badd];
                w0[jj] = lo | (hi << 16);
                unsigned lo1 = (offA1[2*jj]   >= 0) ? (unsigned)sP[offA1[2*jj]   + badd] : 0u;
                unsigned hi1 = (offA1[2*jj+1] >= 0) ? (unsigned)sP[offA1[2*jj+1] + badd] : 0u;
                w1[jj] = lo1 | (hi1 << 16);
            }
            uint4 u0; u0.x = w0[0]; u0.y = w0[1]; u0.z = w0[2]; u0.w = w0[3];
            uint4 u1; u1.x = w1[0]; u1.y = w1[1]; u1.z = w1[2]; u1.w = w1[3];
            b8v a0 = __builtin_bit_cast(b8v, u0);
            b8v a1 = __builtin_bit_cast(b8v, u1);
            #pragma unroll
            for (int nt = 0; nt < 2; ++nt) {
                acc[mt][nt] = __builtin_amdgcn_mfma_f32_16x16x32_bf16(a0, wv[nt][0], acc[mt][nt], 0, 0, 0);
                acc[mt][nt] = __builtin_amdgcn_mfma_f32_16x16x32_bf16(a1, wv[nt][1], acc[mt][nt], 0, 0, 0);
            }
        }
        // Epilogue for this pass: lane holds 4 consecutive px for channel o.
        #pragma unroll
        for (int nt = 0; nt < 2; ++nt) {
            int o = nt*16 + m;
            bool valid = (o < 24);
            float bo = valid ? bias[o] : 0.f;
            #pragma unroll
            for (int mt = 0; mt < 4; ++mt) {
                int pxb = wid*128 + pass*64 + mt*16 + q4*4;
                unsigned l0 = bfbits(acc[mt][nt][0] + bo);
                unsigned l1 = bfbits(acc[mt][nt][1] + bo);
                unsigned l2 = bfbits(acc[mt][nt][2] + bo);
                unsigned l3 = bfbits(acc[mt][nt][3] + bo);
                if (valid) {
                    uint2 pk; pk.x = l0 | (l1 << 16); pk.y = l2 | (l3 << 16);
                    int r = pxb >> 7, xx = pxb & 127;
                    *(uint2*)(c2 + ((size_t)(b*24+o))*PL2 + (size_t)(h0 + r)*W2 + xx) = pk;
                    float f0 = b2f(l0), f1 = b2f(l1), f2 = b2f(l2), f3 = b2f(l3);
                    sAcc[nt] += f0+f1+f2+f3;
                    qAcc[nt] += f0*f0+f1*f1+f2*f2+f3*f3;
                }
            }
        }
    }
    #pragma unroll
    for (int nt = 0; nt < 2; ++nt) {
        int o = nt*16 + m;
        float s = sAcc[nt], q = qAcc[nt];
        s += __shfl_xor(s, 16); q += __shfl_xor(q, 16);
        s += __shfl_xor(s, 32); q += __shfl_xor(q, 32);
        if (q4 == 0 && o < 24) { atomicAdd(&redS[o], s); atomicAdd(&redQ[o], q); }
    }
    __syncthreads();
    if (t < 24) {
        atomicAdd(&mc2[((size_t)b*24 + t)*2],     redS[t]);
        atomicAdd(&mc2[((size_t)b*24 + t)*2 + 1], redQ[t]);
    }
}

// ---------------------------------------------------------------------------
// K8: tconv3 2x2 s2, 24->24 via MFMA, fused gn2+ReLU+pool+SiLU.
// FRAGMENT-DIRECT. 1024 blocks x 128 px.
__global__ __launch_bounds__(256) void k_tconv3(
    const bf* __restrict__ c2, const float* __restrict__ mc2,
    const float* __restrict__ g2, const float* __restrict__ be2,
    const float* __restrict__ k3, const float* __restrict__ b3,
    bf* __restrict__ u3, float* __restrict__ mu3)
{
    __shared__ ushortt sW[96*64];
    __shared__ float redS[24], redQ[24];
    __shared__ float ssl[48];
    int t = threadIdx.x;
    int b = blockIdx.x >> 4, pg = blockIdx.x & 15;
    int lane = t & 63, wid = t >> 6;
    int m = lane & 15, q4 = lane >> 4;
    if (t < 24) {
        redS[t] = 0.f; redQ[t] = 0.f;
        float s = mc2[((size_t)b*24 + t)*2], q = mc2[((size_t)b*24 + t)*2 + 1];
        float mean = s * (1.f/PL2);
        float var  = q * (1.f/PL2) - mean*mean;
        float rstd = rsqrtf(var + 1e-5f);
        float sc = g2[t]*rstd;
        ssl[t*2] = sc; ssl[t*2+1] = be2[t] - mean*sc;
    }
    // zero W pad block (logical g=3) per row; data goes to logical 0..2.
    if (t < 96) {
        uint4 z = {0,0,0,0};
        *(uint4*)&sW[t*64 + (((3 ^ (t & 3)) + (t & 4)) << 3)] = z;
    }
    // stage W (division-free): 2304 elems = 24c x 96n, padded to 24 x 128
    #pragma unroll
    for (int j = 0; j < 12; ++j) {
        int i = j*256 + t;                  // < 3072
        int c = i >> 7, n = i & 127;
        if (n < 96)
            sW[n*64 + (((((c >> 3) ^ (n & 3)) + (n & 4)) << 3) | (c & 7))] =
                (ushortt)bfbits(k3[c*96 + n]);
    }
    __syncthreads();
    // MFMA: wave = 32 px x 96 n, single K=32 step; A built in registers.
    b8v wv[6];
    #pragma unroll
    for (int nt = 0; nt < 6; ++nt) {
        int n = nt*16 + m;
        wv[nt] = *(const b8v*)&sW[n*64 + (((q4 ^ (n & 3)) + (n & 4)) << 3)];
    }
    f4v acc[2][6] = {};
    #pragma unroll
    for (int mt = 0; mt < 2; ++mt) {
        int px = wid*32 + mt*16 + m;
        int pix = pg*128 + px;
        int h4 = pix >> 6, w4 = pix & 63;
        const bf* base = c2 + (size_t)b*24*PL2 + (size_t)(2*h4)*W2 + 2*w4;
        uint4 au = {0,0,0,0};
        if (q4 < 3) {
            unsigned pr[4];
            #pragma unroll
            for (int jj = 0; jj < 4; ++jj) {
                unsigned two[2];
                #pragma unroll
                for (int cc = 0; cc < 2; ++cc) {
                    int c = q4*8 + jj*2 + cc;
                    const bf* pp = base + (size_t)c*PL2;
                    unsigned r0 = *(const unsigned*)pp;
                    unsigned r1 = *(const unsigned*)(pp + W2);
                    float sc = ssl[c*2], sh = ssl[c*2+1];
                    float e0 = fmaxf(b2f(r0 & 0xffff)*sc+sh, 0.f);
                    float e1 = fmaxf(b2f(r0 >> 16)   *sc+sh, 0.f);
                    float e2 = fmaxf(b2f(r1 & 0xffff)*sc+sh, 0.f);
                    float e3 = fmaxf(b2f(r1 >> 16)   *sc+sh, 0.f);
                    float mm = fmaxf(fmaxf(e0,e1), fmaxf(e2,e3));
                    mm = mm / (1.f + __expf(-mm));
                    two[cc] = bfbits(mm);
                }
                pr[jj] = two[0] | (two[1] << 16);
            }
            au.x = pr[0]; au.y = pr[1]; au.z = pr[2]; au.w = pr[3];
        }
        b8v av = __builtin_bit_cast(b8v, au);
        #pragma unroll
        for (int nt = 0; nt < 6; ++nt)
            acc[mt][nt] = __builtin_amdgcn_mfma_f32_16x16x32_bf16(av, wv[nt], acc[mt][nt], 0, 0, 0);
    }
    // Epilogue: lane-paired direct global uint4 stores + register stats.
    float sAcc[6] = {}, qAcc[6] = {};
    int qq = m & 1;
    #pragma unroll
    for (int nt = 0; nt < 6; ++nt) {
        int n = nt*16 + m;
        int o = n >> 2, d = (n >> 1) & 1;
        float bo = b3[o];
        #pragma unroll
        for (int mt = 0; mt < 2; ++mt) {
            int pxb = wid*32 + mt*16 + q4*4;
            unsigned wds[4];
            float s = 0.f, q = 0.f;
            #pragma unroll
            for (int r = 0; r < 4; ++r) {
                float v = acc[mt][nt][r] + bo;
                float vp = __shfl_xor(v, 1);
                unsigned lo = bfbits(v), hi = bfbits(vp);
                wds[r] = lo | (hi << 16);
                float f0 = b2f(lo), f1 = b2f(hi);
                s += f0 + f1;
                q += f0*f0 + f1*f1;
            }
            if (qq == 0) {
                int pix = pg*128 + pxb;
                int h4 = pix >> 6;
                int w4 = pix & 63;
                uint4 pk; pk.x = wds[0]; pk.y = wds[1]; pk.z = wds[2]; pk.w = wds[3];
                *(uint4*)(u3 + ((size_t)(b*24 + o))*PL2 + (size_t)(2*h4 + d)*W2 + 2*w4) = pk;
                sAcc[nt] += s; qAcc[nt] += q;
            }
        }
    }
    #pragma unroll
    for (int nt = 0; nt < 6; ++nt) {
        float s = sAcc[nt], q = qAcc[nt];
        s += __shfl_xor(s, 2);  q += __shfl_xor(q, 2);
        s += __shfl_xor(s, 16); q += __shfl_xor(q, 16);
        s += __shfl_xor(s, 32); q += __shfl_xor(q, 32);
        if ((lane & 51) == 0) {            // m&3==0 && q4==0
            int o = nt*4 + (m >> 2);
            atomicAdd(&redS[o], s);
            atomicAdd(&redQ[o], q);
        }
    }
    __syncthreads();
    if (t < 24) {
        atomicAdd(&mu3[((size_t)b*24 + t)*2],     redS[t]);
        atomicAdd(&mu3[((size_t)b*24 + t)*2 + 1], redQ[t]);
    }
}

// ---------------------------------------------------------------------------
// K10: gn3-fused tconv4 2x2 s2, 48->12 via MFMA. FRAGMENT-DIRECT (scalar
// ushort channel-gather — round-8's paired-pixel shfl variant REVERTED:
// __shfl_xor routes through the LDS crossbar (434K bank conflicts, +14 us).
// 2048 blocks.
__global__ __launch_bounds__(256) void k_tconv4(
    const bf* __restrict__ c2, const bf* __restrict__ u3,
    const float* __restrict__ mc2, const float* __restrict__ mu3,
    const float* __restrict__ g3, const float* __restrict__ be3,
    const float* __restrict__ k4, const float* __restrict__ bias4,
    bf* __restrict__ u4, float* __restrict__ mu4)
{
    __shared__ ushortt sW[48*64];    // [n][kb^(n&7) blocks of 8]
    __shared__ float redS[12], redQ[12];
    __shared__ float ssl[96];
    int t = threadIdx.x;
    int b = blockIdx.x >> 5, pg = blockIdx.x & 31;
    int lane = t & 63, wid = t >> 6;
    int m = lane & 15, q4 = lane >> 4;
    if (t < 12) { redS[t] = 0.f; redQ[t] = 0.f; }
    if (t < 6) {
        float s = 0.f, q = 0.f;
        #pragma unroll
        for (int cl = 0; cl < 8; ++cl) {
            int gc = t*8 + cl;
            const float* p = (gc < 24) ? mc2 + ((size_t)b*24 + gc)*2
                                       : mu3 + ((size_t)b*24 + gc - 24)*2;
            s += p[0]; q += p[1];
        }
        float inv_n = 1.f/((float)PL2*8.f);
        float mean = s*inv_n;
        float var  = q*inv_n - mean*mean;
        float rstd = rsqrtf(var + 1e-5f);
        #pragma unroll
        for (int cl = 0; cl < 8; ++cl) {
            int gc = t*8 + cl;
            float sc = g3[gc]*rstd;
            ssl[gc*2] = sc; ssl[gc*2+1] = be3[gc] - mean*sc;
        }
    }
    // stage W (division-free): 2304 = 48c x 48n, padded to 48 x 64
    #pragma unroll
    for (int j = 0; j < 12; ++j) {
        int i = j*256 + t;                 // < 3072
        int c = i >> 6, n = i & 63;
        if (n < 48)
            sW[n*64 + ((((c >> 3) ^ (n & 7)) << 3) | (c & 7))] =
                (ushortt)bfbits(k4[c*48 + n]);
    }
    if (t < 96) {                          // zero pad blocks kb=6,7
        uint4 z = {0,0,0,0};
        int n = t >> 1, kb = 6 + (t & 1);
        *(uint4*)&sW[n*64 + ((kb ^ (n & 7)) << 3)] = z;
    }
    __syncthreads();
    // MFMA: wave = 64 px x 48 n, K=64; A built in registers from global.
    b8v bfr[3][2];
    #pragma unroll
    for (int nt = 0; nt < 3; ++nt) {
        int n = nt*16 + m;
        #pragma unroll
        for (int ks = 0; ks < 2; ++ks)
            bfr[nt][ks] = *(const b8v*)&sW[n*64 + (((ks*4 + q4) ^ (n & 7)) << 3)];
    }
    f4v acc[4][3] = {};
    #pragma unroll
    for (int mt = 0; mt < 4; ++mt) {
        int px = wid*64 + mt*16 + m;
        int pix = pg*256 + px;
        const ushortt* pc2 = (const ushortt*)c2 + (size_t)b*24*PL2 + pix;
        const ushortt* pu3 = (const ushortt*)u3 + (size_t)b*24*PL2 + pix;
        unsigned pr[4];
        #pragma unroll
        for (int jj = 0; jj < 4; ++jj) {
            unsigned two[2];
            #pragma unroll
            for (int cc = 0; cc < 2; ++cc) {
                int c = q4*8 + jj*2 + cc;      // 0..31
                unsigned raw = (c < 24) ? (unsigned)pc2[(size_t)c*PL2]
                                        : (unsigned)pu3[(size_t)(c-24)*PL2];
                float v = b2f(raw)*ssl[2*c] + ssl[2*c+1];
                two[cc] = bfbits(v);
            }
            pr[jj] = two[0] | (two[1] << 16);
        }
        uint4 u0; u0.x = pr[0]; u0.y = pr[1]; u0.z = pr[2]; u0.w = pr[3];
        b8v a0 = __builtin_bit_cast(b8v, u0);
        uint4 u1 = {0,0,0,0};
        if (q4 < 2) {
            unsigned pr1[4];
            #pragma unroll
            for (int jj = 0; jj < 4; ++jj) {
                unsigned two[2];
                #pragma unroll
                for (int cc = 0; cc < 2; ++cc) {
                    int c = 32 + q4*8 + jj*2 + cc; // 32..47 -> all from u3
                    unsigned raw = (unsigned)pu3[(size_t)(c-24)*PL2];
                    float v = b2f(raw)*ssl[2*c] + ssl[2*c+1];
                    two[cc] = bfbits(v);
                }
                pr1[jj] = two[0] | (two[1] << 16);
            }
            u1.x = pr1[0]; u1.y = pr1[1]; u1.z = pr1[2]; u1.w = pr1[3];
        }
        b8v a1 = __builtin_bit_cast(b8v, u1);
        #pragma unroll
        for (int nt = 0; nt < 3; ++nt) {
            acc[mt][nt] = __builtin_amdgcn_mfma_f32_16x16x32_bf16(a0, bfr[nt][0], acc[mt][nt], 0, 0, 0);
            acc[mt][nt] = __builtin_amdgcn_mfma_f32_16x16x32_bf16(a1, bfr[nt][1], acc[mt][nt], 0, 0, 0);
        }
    }
    // Epilogue: lane-paired direct global uint4 stores + register stats.
    float sAcc[3] = {0.f, 0.f, 0.f}, qAcc[3] = {0.f, 0.f, 0.f};
    int qq = m & 1;
    #pragma unroll
    for (int nt = 0; nt < 3; ++nt) {
        int n = nt*16 + m;
        int o = n >> 2, d = (n >> 1) & 1;
        float bo = bias4[o];
        #pragma unroll
        for (int mt = 0; mt < 4; ++mt) {
            int pxb = wid*64 + mt*16 + q4*4;
            unsigned wds[4];
            float s = 0.f, q = 0.f;
            #pragma unroll
            for (int r = 0; r < 4; ++r) {
                float v = acc[mt][nt][r] + bo;
                float vp = __shfl_xor(v, 1);
                unsigned lo = bfbits(v), hi = bfbits(vp);
                wds[r] = lo | (hi << 16);
                float f0 = b2f(lo), f1 = b2f(hi);
                s += f0 + f1;
                q += f0*f0 + f1*f1;
            }
            if (qq == 0) {
                int h2 = (pg*256 + pxb) >> 7;
                int w0 = pxb & 127;
                uint4 pk; pk.x = wds[0]; pk.y = wds[1]; pk.z = wds[2]; pk.w = wds[3];
                *(uint4*)(u4 + (((size_t)(b*12 + o))*HH + 2*h2 + d)*EE + 2*w0) = pk;
                sAcc[nt] += s; qAcc[nt] += q;
            }
        }
    }
    #pragma unroll
    for (int nt = 0; nt < 3; ++nt) {
        float s = sAcc[nt], q = qAcc[nt];
        s += __shfl_xor(s, 2);  q += __shfl_xor(q, 2);
        s += __shfl_xor(s, 16); q += __shfl_xor(q, 16);
        s += __shfl_xor(s, 32); q += __shfl_xor(q, 32);
        if ((lane & 51) == 0) {
            int o = nt*4 + (m >> 2);
            atomicAdd(&redS[o], s);
            atomicAdd(&redQ[o], q);
        }
    }
    __syncthreads();
    if (t < 12) {
        atomicAdd(&mu4[((size_t)b*12 + t)*2],     redS[t]);
        atomicAdd(&mu4[((size_t)b*12 + t)*2 + 1], redQ[t]);
    }
}

// ---------------------------------------------------------------------------
// K12: gn4-fused 1x1 conv 18->6. gn4 prologue from mc1+mu4. 8 px/thread,
// uint4 loads/stores. Fused u5 stats. 1024 blocks.
__global__ __launch_bounds__(256) void k_conv1x1_u5(
    const bf* __restrict__ c1, const bf* __restrict__ u4,
    const float* __restrict__ mc1, const float* __restrict__ mu4,
    const float* __restrict__ g4, const float* __restrict__ be4,
    const float* __restrict__ k, const float* __restrict__ bias,
    bf* __restrict__ u5, float* __restrict__ mu5)
{
    __shared__ float red[4][6][2];
    __shared__ float ssl[36];
    int t = threadIdx.x;
    int b  = blockIdx.x >> 4;
    int pg = blockIdx.x & 15;
    int pix = pg*2048 + t*8;
    int lane = t & 63, wid = t >> 6;
    if (t < 6) {
        float s = 0.f, q = 0.f;
        #pragma unroll
        for (int cl = 0; cl < 3; ++cl) {
            int gc = t*3 + cl;
            const float* p = (gc < 6) ? mc1 + ((size_t)b*6 + gc)*2
                                      : mu4 + ((size_t)b*12 + gc - 6)*2;
            s += p[0]; q += p[1];
        }
        float inv_n = 1.f/((float)HP*3.f);
        float mean = s*inv_n;
        float var  = q*inv_n - mean*mean;
        float rstd = rsqrtf(var + 1e-5f);
        #pragma unroll
        for (int cl = 0; cl < 3; ++cl) {
            int gc = t*3 + cl;
            float sc = g4[gc]*rstd;
            ssl[gc*2] = sc; ssl[gc*2+1] = be4[gc] - mean*sc;
        }
    }
    __syncthreads();
    const bf* c1p = c1 + ((size_t)b*6)*HP + pix;
    const bf* u4p = u4 + ((size_t)b*12)*HP + pix;
    float acc[6][8];
    #pragma unroll
    for (int o = 0; o < 6; ++o) {
        float bv = bias[o];
        #pragma unroll
        for (int j = 0; j < 8; ++j) acc[o][j] = bv;
    }
    #pragma unroll
    for (int c = 0; c < 18; ++c) {
        uint4 r = (c < 6) ? *(const uint4*)(c1p + (size_t)c*HP)
                          : *(const uint4*)(u4p + (size_t)(c-6)*HP);
        float sc = ssl[2*c], sh = ssl[2*c+1];
        float v[8];
        v[0] = b2f(r.x & 0xffff)*sc + sh;  v[1] = b2f(r.x >> 16)*sc + sh;
        v[2] = b2f(r.y & 0xffff)*sc + sh;  v[3] = b2f(r.y >> 16)*sc + sh;
        v[4] = b2f(r.z & 0xffff)*sc + sh;  v[5] = b2f(r.z >> 16)*sc + sh;
        v[6] = b2f(r.w & 0xffff)*sc + sh;  v[7] = b2f(r.w >> 16)*sc + sh;
        #pragma unroll
        for (int o = 0; o < 6; ++o) {
            float wv = k[o*18 + c];
            #pragma unroll
            for (int j = 0; j < 8; ++j) acc[o][j] += v[j]*wv;
        }
    }
    #pragma unroll
    for (int o = 0; o < 6; ++o) {
        uint4 pk;
        pk.x = bfbits(acc[o][0]) | (bfbits(acc[o][1]) << 16);
        pk.y = bfbits(acc[o][2]) | (bfbits(acc[o][3]) << 16);
        pk.z = bfbits(acc[o][4]) | (bfbits(acc[o][5]) << 16);
        pk.w = bfbits(acc[o][6]) | (bfbits(acc[o][7]) << 16);
        *(uint4*)(u5 + ((size_t)(b*6+o))*HP + pix) = pk;
        float s = 0.f, q = 0.f;
        #pragma unroll
        for (int j = 0; j < 8; ++j) { s += acc[o][j]; q += acc[o][j]*acc[o][j]; }
        wred2(s, q);
        if (lane == 0) { red[wid][o][0] = s; red[wid][o][1] = q; }
    }
    __syncthreads();
    if (t < 6) {
        float S = 0.f, Q = 0.f;
        #pragma unroll
        for (int wv = 0; wv < 4; ++wv) { S += red[wv][t][0]; Q += red[wv][t][1]; }
        atomicAdd(&mu5[((size_t)b*6 + t)*2],     S);
        atomicAdd(&mu5[((size_t)b*6 + t)*2 + 1], Q);
    }
}

// ---------------------------------------------------------------------------
// K14: gn5-fused final 1x1 conv (6->1) + divide by std(t). gn5 in prologue.
// 8 px/thread, uint4 loads, 2x float4 stores. 1024 blocks.
__global__ __launch_bounds__(256) void k_final(
    const bf* __restrict__ u5, const float* __restrict__ mu5,
    const float* __restrict__ g5, const float* __restrict__ be5,
    const float* __restrict__ k, const float* __restrict__ bias,
    const float* __restrict__ t, float* __restrict__ out)
{
    __shared__ float ssl[12];
    int tt = threadIdx.x;
    int b = blockIdx.x >> 4;
    int pix = ((blockIdx.x & 15)*256 + tt)*8;
    if (tt < 6) {
        float s = mu5[((size_t)b*6 + tt)*2], q = mu5[((size_t)b*6 + tt)*2 + 1];
        float mean = s * (1.f/HP);
        float var  = q * (1.f/HP) - mean*mean;
        float rstd = rsqrtf(var + 1e-5f);
        float sc = g5[tt]*rstd;
        ssl[tt*2] = sc; ssl[tt*2+1] = be5[tt] - mean*sc;
    }
    __syncthreads();
    const bf* up = u5 + (size_t)b*6*HP + pix;
    float bv = bias[0];
    float a[8];
    #pragma unroll
    for (int j = 0; j < 8; ++j) a[j] = bv;
    #pragma unroll
    for (int c = 0; c < 6; ++c) {
        uint4 r = *(const uint4*)(up + (size_t)c*HP);
        float sc = ssl[2*c], sh = ssl[2*c+1];
        float wv = k[c];
        a[0] += (b2f(r.x & 0xffff)*sc + sh) * wv;
        a[1] += (b2f(r.x >> 16)   *sc + sh) * wv;
        a[2] += (b2f(r.y & 0xffff)*sc + sh) * wv;
        a[3] += (b2f(r.y >> 16)   *sc + sh) * wv;
        a[4] += (b2f(r.z & 0xffff)*sc + sh) * wv;
        a[5] += (b2f(r.z >> 16)   *sc + sh) * wv;
        a[6] += (b2f(r.w & 0xffff)*sc + sh) * wv;
        a[7] += (b2f(r.w >> 16)   *sc + sh) * wv;
    }
    float tb = t[b];
    const float lns = 3.2188758248682007492f;
    float var = (__expf(2.f*tb*lns) - 1.f) / (2.f*lns);
    float rs = rsqrtf(var);
    float4 o0; o0.x = a[0]*rs; o0.y = a[1]*rs; o0.z = a[2]*rs; o0.w = a[3]*rs;
    float4 o1; o1.x = a[4]*rs; o1.y = a[5]*rs; o1.z = a[6]*rs; o1.w = a[7]*rs;
    float* op = out + (size_t)b*HP + pix;
    *(float4*)op       = o0;
    *(float4*)(op + 4) = o1;
}

// ---------------------------------------------------------------------------
extern "C" void kernel_launch(void* const* d_in, const int* in_sizes, int n_in,
                              void* d_out, int out_size, void* d_ws, size_t ws_size,
                              hipStream_t stream)
{
    const float* x       = (const float*)d_in[0];
    const float* t       = (const float*)d_in[1];
    const float* Wf      = (const float*)d_in[2];
    const float* fc1_w   = (const float*)d_in[3];
    const float* fc1_b   = (const float*)d_in[4];
    const float* conv1_k = (const float*)d_in[5];
    const float* conv1_b = (const float*)d_in[6];
    const float* gn1_g   = (const float*)d_in[7];
    const float* gn1_b   = (const float*)d_in[8];
    const float* conv2_k = (const float*)d_in[9];
    const float* conv2_b = (const float*)d_in[10];
    const float* gn2_g   = (const float*)d_in[11];
    const float* gn2_b   = (const float*)d_in[12];
    const float* t3_k    = (const float*)d_in[13];
    const float* t3_b    = (const float*)d_in[14];
    const float* gn3_g   = (const float*)d_in[15];
    const float* gn3_b   = (const float*)d_in[16];
    const float* t4_k    = (const float*)d_in[17];
    const float* t4_b    = (const float*)d_in[18];
    const float* gn4_g   = (const float*)d_in[19];
    const float* gn4_b   = (const float*)d_in[20];
    const float* t5_k    = (const float*)d_in[21];
    const float* t5_b    = (const float*)d_in[22];
    const float* gn5_g   = (const float*)d_in[23];
    const float* gn5_b   = (const float*)d_in[24];
    const float* fin_k   = (const float*)d_in[25];
    const float* fin_b   = (const float*)d_in[26];

    bf* wsb = (bf*)d_ws;
    bf* c1 = wsb;                          // conv1..conv1x1
    bf* c2 = wsb + 12582912;               // conv2..tconv4
    bf* u3 = wsb + 25165824;               // tconv3..tconv4
    bf* u4 = wsb + 37748736;               // tconv4..conv1x1
    bf* xf = wsb + 39845888;               // fc1..conv1 (in u4 region)
    bf* u5 = wsb + 12582912;               // reuses c2, conv1x1..final
    float* mb = (float*)(wsb + 62914560);  // raw channel sums
    float* mc1 = mb;            // 768
    float* mc2 = mb + 768;      // 3072
    float* mu3 = mb + 3840;     // 3072
    float* mu4 = mb + 6912;     // 1536
    float* mu5 = mb + 8448;     // 768

    k_fourier_fc1<<<512, 256, 0, stream>>>(x, Wf, fc1_w, fc1_b, xf, mb);
    k_conv1<<<1024, 256, 0, stream>>>(xf, conv1_k, conv1_b, c1, mc1);
    k_conv2<<<1024, 256, 0, stream>>>(c1, mc1, gn1_g, gn1_b,
                                      conv2_k, conv2_b, c2, mc2);
    k_tconv3<<<1024, 256, 0, stream>>>(c2, mc2, gn2_g, gn2_b,
                                       t3_k, t3_b, u3, mu3);
    k_tconv4<<<2048, 256, 0, stream>>>(c2, u3, mc2, mu3, gn3_g, gn3_b,
                                       t4_k, t4_b, u4, mu4);
    k_conv1x1_u5<<<1024, 256, 0, stream>>>(c1, u4, mc1, mu4, gn4_g, gn4_b,
                                           t5_k, t5_b, u5, mu5);
    k_final<<<1024, 256, 0, stream>>>(u5, mu5, gn5_g, gn5_b,
                                      fin_k, fin_b, t, (float*)d_out);
}

// Round 10
// 219.127 us; speedup vs baseline: 1.0928x; 1.0928x over previous
//
#include <hip/hip_runtime.h>
#include <hip/hip_bf16.h>
#include <math.h>

#define BB 64
#define HH 128
#define WW 128
#define EE 256
#define HP (HH*EE)        // 32768
#define H2 64
#define W2 128
#define PL2 (H2*W2)       // 8192
#define H4 32
#define W4 64
#define PL4 (H4*W4)       // 2048

typedef __hip_bfloat16 bf;
typedef unsigned short ushortt;
typedef __attribute__((ext_vector_type(8))) __bf16 b8v;
typedef __attribute__((ext_vector_type(4))) float f4v;

__device__ __forceinline__ float tof(bf v)    { return __bfloat162float(v); }
__device__ __forceinline__ bf    tob(float v) { return __float2bfloat16(v); }
__device__ __forceinline__ unsigned int bfbits(float v) {
    return (unsigned int)__builtin_bit_cast(ushortt, __float2bfloat16(v));
}
__device__ __forceinline__ float b2f(unsigned int u16) {
    unsigned int x = u16 << 16;
    return __builtin_bit_cast(float, x);
}
__device__ __forceinline__ void wred2(float& s, float& q) {
    #pragma unroll
    for (int m = 32; m; m >>= 1) {
        s += __shfl_xor(s, m);
        q += __shfl_xor(q, m);
    }
}

// ---------------------------------------------------------------------------
// K1: fused Fourier features + fc1 GEMM via MFMA. 512 blocks.
// Prologue grid-stride zeroes the stats buffer.
__global__ __launch_bounds__(256) void k_fourier_fc1(
    const float* __restrict__ x, const float* __restrict__ Wf,
    const float* __restrict__ fc1_w, const float* __restrict__ fc1_b,
    bf* __restrict__ xf, float* __restrict__ mb)
{
    __shared__ ushortt sA[64*264];
    __shared__ ushortt sB[64*264];
    int t = threadIdx.x;
    for (int i = blockIdx.x*256 + t; i < 9280; i += 512*256) mb[i] = 0.f;
    int rb = blockIdx.x >> 2, cb = blockIdx.x & 3;
    int row0 = rb*64, col0 = cb*64;
    const float TP = 6.2831853071795864769f;
    for (int it = 0; it < 32; ++it) {       // 8192 = 64 rows x 128 w
        int i = it*256 + t;
        int r = i >> 7, w = i & 127;
        int rg = row0 + r;
        float p = x[(size_t)rg*WW + w] * Wf[(size_t)(rg & (HH-1))*WW + w] * TP;
        sA[r*264 + w]       = (ushortt)bfbits(__sinf(p));
        sA[r*264 + 128 + w] = (ushortt)bfbits(__cosf(p));
    }
    #pragma unroll
    for (int it = 0; it < 16; ++it) {       // B: fp32 -> bf16
        int i = it*256 + t;
        int o = i >> 6, c4 = i & 63;
        float4 w4 = *(const float4*)(fc1_w + (size_t)(col0 + o)*EE + c4*4);
        uint2 pk;
        pk.x = bfbits(w4.x) | (bfbits(w4.y) << 16);
        pk.y = bfbits(w4.z) | (bfbits(w4.w) << 16);
        *(uint2*)&sB[o*264 + c4*4] = pk;
    }
    __syncthreads();
    int lane = t & 63, wid = t >> 6;
    int m = lane & 15, kq = (lane >> 4) * 8;
    f4v acc[4] = {};
    const ushortt* aBase = &sA[(wid*16 + m)*264 + kq];
    #pragma unroll
    for (int k0 = 0; k0 < 8; ++k0) {
        b8v av = *(const b8v*)(aBase + k0*32);
        #pragma unroll
        for (int t4 = 0; t4 < 4; ++t4) {
            b8v bv = *(const b8v*)&sB[(t4*16 + m)*264 + k0*32 + kq];
            acc[t4] = __builtin_amdgcn_mfma_f32_16x16x32_bf16(av, bv, acc[t4], 0, 0, 0);
        }
    }
    int rbase = row0 + wid*16 + (lane >> 4)*4;
    #pragma unroll
    for (int t4 = 0; t4 < 4; ++t4) {
        int col = col0 + t4*16 + m;
        float bias = fc1_b[col];
        #pragma unroll
        for (int r = 0; r < 4; ++r)
            xf[(size_t)(rbase + r)*EE + col] = tob(acc[t4][r] + bias);
    }
}

// ---------------------------------------------------------------------------
// K2: conv1 3x3, 1->6, LDS-staged rows, 4 px/thread. 2048 blocks. Fused gn1
// stats. XCD-swizzled blockIdx. (Round-8's 8-row variant REVERTED: halving
// block count + doubling serial work cost ~14 us — conv1 is latency-bound.)
__global__ __launch_bounds__(256) void k_conv1(
    const bf* __restrict__ xf, const float* __restrict__ k,
    const float* __restrict__ bias, bf* __restrict__ c1, float* __restrict__ mc1)
{
    __shared__ ushortt sT[6*272];    // 6 rows, data at [8..263], zero halos
    __shared__ float red[4][6][2];
    int t = threadIdx.x;
    int bid = ((blockIdx.x & 7) << 8) | (blockIdx.x >> 3);   // XCD swizzle
    int ht = bid & 31, b = bid >> 5;
    int h0 = ht*4;
    const bf* src = xf + (size_t)b*HP;
    if (t < 192) {
        int r = t >> 5, i = t & 31;
        int gy = h0 - 1 + r;
        uint4 v = {0,0,0,0};
        if (gy >= 0 && gy < HH) v = *(const uint4*)(src + (size_t)gy*EE + i*8);
        *(uint4*)&sT[r*272 + 8 + i*8] = v;
    } else if (t < 204) {
        int e = t - 192;
        int r = e >> 1, s = e & 1;
        uint4 z = {0,0,0,0};
        *(uint4*)&sT[r*272 + s*264] = z;
    }
    __syncthreads();
    int wq = (t & 63)*4, hl = t >> 6;
    int lane = t & 63, wid = t >> 6;
    float v[3][6];
    #pragma unroll
    for (int ky = 0; ky < 3; ++ky)
      #pragma unroll
      for (int j = 0; j < 6; ++j)
        v[ky][j] = b2f((unsigned)sT[(hl+ky)*272 + 7 + wq + j]);
    int h = h0 + hl;
    #pragma unroll
    for (int o = 0; o < 6; ++o) {
        float bv = bias[o];
        float a0=bv, a1=bv, a2=bv, a3=bv;
        #pragma unroll
        for (int ky = 0; ky < 3; ++ky)
          #pragma unroll
          for (int kx = 0; kx < 3; ++kx) {
            float wv = k[o*9 + ky*3 + kx];
            a0 += v[ky][kx+0]*wv;
            a1 += v[ky][kx+1]*wv;
            a2 += v[ky][kx+2]*wv;
            a3 += v[ky][kx+3]*wv;
          }
        uint2 pk;
        pk.x = bfbits(a0) | (bfbits(a1) << 16);
        pk.y = bfbits(a2) | (bfbits(a3) << 16);
        *(uint2*)(c1 + ((size_t)(b*6+o)*HH + h)*EE + wq) = pk;
        float s = a0+a1+a2+a3, q = a0*a0+a1*a1+a2*a2+a3*a3;
        wred2(s, q);
        if (lane == 0) { red[wid][o][0] = s; red[wid][o][1] = q; }
    }
    __syncthreads();
    if (t < 6) {
        float S = 0.f, Q = 0.f;
        #pragma unroll
        for (int wv = 0; wv < 4; ++wv) { S += red[wv][t][0]; Q += red[wv][t][1]; }
        atomicAdd(&mc1[((size_t)b*6 + t)*2],     S);
        atomicAdd(&mc1[((size_t)b*6 + t)*2 + 1], Q);
    }
}

// ---------------------------------------------------------------------------
// K5: conv2 3x3, 6->24 via MFMA implicit GEMM, fused gn1+ReLU+pool staging.
// FRAGMENT-DIRECT (magic-div offsets). 4 output rows/block, 1024 blocks.
__global__ __launch_bounds__(256) void k_conv2(
    const bf* __restrict__ c1, const float* __restrict__ mc1,
    const float* __restrict__ g1, const float* __restrict__ be1,
    const float* __restrict__ kw, const float* __restrict__ bias,
    bf* __restrict__ c2, float* __restrict__ mc2)
{
    __shared__ ushortt sW[32*64];
    __shared__ ushortt sP[6*6*136];    // 6 ch x 6 pooled rows x 136 (halo'd)
    __shared__ float ssl[12];
    __shared__ float redS[24], redQ[24];
    int t = threadIdx.x;
    int bid = ((blockIdx.x & 7) << 7) | (blockIdx.x >> 3);   // XCD swizzle (1024)
    int ht = bid & 15, b = bid >> 4;
    int h0 = ht*4;                     // output rows h0..h0+3 (of 64)
    int lane = t & 63, wid = t >> 6;
    int m = lane & 15, q4 = lane >> 4;
    if (t < 24) { redS[t] = 0.f; redQ[t] = 0.f; }
    if (t < 6) {
        float s = mc1[((size_t)b*6 + t)*2], q = mc1[((size_t)b*6 + t)*2 + 1];
        float mean = s * (1.f/HP);
        float var  = q * (1.f/HP) - mean*mean;
        float rstd = rsqrtf(var + 1e-5f);
        float sc = g1[t]*rstd;
        ssl[t*2] = sc; ssl[t*2+1] = be1[t] - mean*sc;
    }
    for (int i = t; i < 1024; i += 256) ((unsigned*)sW)[i] = 0;   // zero W
    if (t < 96) {                      // halo cols (gx=-1,128): 6ch x 6rows x 2
        int c = t >> 4, e = t & 15;
        if (e < 12) {
            int ry = e >> 1, rx = (e & 1) ? 129 : 0;
            sP[c*816 + ry*136 + rx] = 0;
        }
    }
    __syncthreads();
    // stage pooled tile main cols (gn1+ReLU+pool): 6 ch x 6 rows x 128 cols
    #pragma unroll
    for (int j = 0; j < 18; ++j) {
        int i = j*256 + t;             // < 4608 = 6*768
        int c = (i*2731) >> 21;        // i/768 for i<4608
        int rem = i - c*768;
        int ry = rem >> 7, gx = rem & 127;
        int gy = h0 - 1 + ry;
        float v = 0.f;
        if (gy >= 0 && gy < H2) {
            const bf* pp = c1 + ((size_t)(b*6+c)*HH + 2*gy)*EE + 2*gx;
            unsigned r0 = *(const unsigned*)pp;
            unsigned r1 = *(const unsigned*)(pp + EE);
            float sc = ssl[c*2], sh = ssl[c*2+1];
            float e0 = fmaxf(b2f(r0 & 0xffff)*sc+sh, 0.f);
            float e1 = fmaxf(b2f(r0 >> 16)   *sc+sh, 0.f);
            float e2 = fmaxf(b2f(r1 & 0xffff)*sc+sh, 0.f);
            float e3 = fmaxf(b2f(r1 >> 16)   *sc+sh, 0.f);
            v = fmaxf(fmaxf(e0,e1), fmaxf(e2,e3));
        }
        sP[c*816 + ry*136 + gx + 1] = (ushortt)bfbits(v);
    }
    // stage W: kw[o][kk] -> sW[o][swizzled block (kk>>3)^(o&7), elem kk&7]
    #pragma unroll
    for (int j = 0; j < 6; ++j) {
        int i = j*256 + t;             // < 1536 = 24*64
        int o = i >> 6, kk = i & 63;
        if (kk < 54)
            sW[o*64 + ((((kk >> 3) ^ (o & 7)) << 3) | (kk & 7))] =
                (ushortt)bfbits(kw[o*54 + kk]);
    }
    __syncthreads();
    b8v wv[2][2];
    #pragma unroll
    for (int nt = 0; nt < 2; ++nt) {
        int o = nt*16 + m;
        #pragma unroll
        for (int ks = 0; ks < 2; ++ks)
            wv[nt][ks] = *(const b8v*)&sW[o*64 + (((ks*4 + q4) ^ (o & 7)) << 3)];
    }
    // Per-lane A-fragment sP offsets: k = ks*32 + q4*8 + j -> (c,y,x)
    int offA0[8], offA1[8];
    #pragma unroll
    for (int j = 0; j < 8; ++j) {
        int k0 = q4*8 + j;             // 0..31, always valid
        int c = (k0*57) >> 9;
        int r9 = k0 - 9*c;
        int y = (r9*11) >> 5;
        int xk = r9 - 3*y;
        offA0[j] = c*816 + y*136 + xk;
        int k1 = 32 + q4*8 + j;        // 32..63, valid iff < 54
        c = (k1*57) >> 9;
        r9 = k1 - 9*c;
        y = (r9*11) >> 5;
        xk = r9 - 3*y;
        offA1[j] = (k1 < 54) ? (c*816 + y*136 + xk) : -1;
    }
    float sAcc[2] = {0.f, 0.f}, qAcc[2] = {0.f, 0.f};
    #pragma unroll
    for (int pass = 0; pass < 2; ++pass) {
        f4v acc[4][2] = {};
        #pragma unroll
        for (int mt = 0; mt < 4; ++mt) {
            int px = wid*128 + pass*64 + mt*16 + m;     // 0..511
            int badd = (px >> 7)*136 + (px & 127);
            unsigned w0[4], w1[4];
            #pragma unroll
            for (int jj = 0; jj < 4; ++jj) {
                unsigned lo  = sP[offA0[2*jj]   + badd];
                unsigned hi  = sP[offA0[2*jj+1] + badd];
                w0[jj] = lo | (hi << 16);
                unsigned lo1 = (offA1[2*jj]   >= 0) ? (unsigned)sP[offA1[2*jj]   + badd] : 0u;
                unsigned hi1 = (offA1[2*jj+1] >= 0) ? (unsigned)sP[offA1[2*jj+1] + badd] : 0u;
                w1[jj] = lo1 | (hi1 << 16);
            }
            uint4 u0; u0.x = w0[0]; u0.y = w0[1]; u0.z = w0[2]; u0.w = w0[3];
            uint4 u1; u1.x = w1[0]; u1.y = w1[1]; u1.z = w1[2]; u1.w = w1[3];
            b8v a0 = __builtin_bit_cast(b8v, u0);
            b8v a1 = __builtin_bit_cast(b8v, u1);
            #pragma unroll
            for (int nt = 0; nt < 2; ++nt) {
                acc[mt][nt] = __builtin_amdgcn_mfma_f32_16x16x32_bf16(a0, wv[nt][0], acc[mt][nt], 0, 0, 0);
                acc[mt][nt] = __builtin_amdgcn_mfma_f32_16x16x32_bf16(a1, wv[nt][1], acc[mt][nt], 0, 0, 0);
            }
        }
        // Epilogue for this pass: lane holds 4 consecutive px for channel o.
        #pragma unroll
        for (int nt = 0; nt < 2; ++nt) {
            int o = nt*16 + m;
            bool valid = (o < 24);
            float bo = valid ? bias[o] : 0.f;
            #pragma unroll
            for (int mt = 0; mt < 4; ++mt) {
                int pxb = wid*128 + pass*64 + mt*16 + q4*4;
                unsigned l0 = bfbits(acc[mt][nt][0] + bo);
                unsigned l1 = bfbits(acc[mt][nt][1] + bo);
                unsigned l2 = bfbits(acc[mt][nt][2] + bo);
                unsigned l3 = bfbits(acc[mt][nt][3] + bo);
                if (valid) {
                    uint2 pk; pk.x = l0 | (l1 << 16); pk.y = l2 | (l3 << 16);
                    int r = pxb >> 7, xx = pxb & 127;
                    *(uint2*)(c2 + ((size_t)(b*24+o))*PL2 + (size_t)(h0 + r)*W2 + xx) = pk;
                    float f0 = b2f(l0), f1 = b2f(l1), f2 = b2f(l2), f3 = b2f(l3);
                    sAcc[nt] += f0+f1+f2+f3;
                    qAcc[nt] += f0*f0+f1*f1+f2*f2+f3*f3;
                }
            }
        }
    }
    #pragma unroll
    for (int nt = 0; nt < 2; ++nt) {
        int o = nt*16 + m;
        float s = sAcc[nt], q = qAcc[nt];
        s += __shfl_xor(s, 16); q += __shfl_xor(q, 16);
        s += __shfl_xor(s, 32); q += __shfl_xor(q, 32);
        if (q4 == 0 && o < 24) { atomicAdd(&redS[o], s); atomicAdd(&redQ[o], q); }
    }
    __syncthreads();
    if (t < 24) {
        atomicAdd(&mc2[((size_t)b*24 + t)*2],     redS[t]);
        atomicAdd(&mc2[((size_t)b*24 + t)*2 + 1], redQ[t]);
    }
}

// ---------------------------------------------------------------------------
// K8: tconv3 2x2 s2, 24->24 via MFMA, fused gn2+ReLU+pool+SiLU.
// FRAGMENT-DIRECT. 1024 blocks x 128 px.
__global__ __launch_bounds__(256) void k_tconv3(
    const bf* __restrict__ c2, const float* __restrict__ mc2,
    const float* __restrict__ g2, const float* __restrict__ be2,
    const float* __restrict__ k3, const float* __restrict__ b3,
    bf* __restrict__ u3, float* __restrict__ mu3)
{
    __shared__ ushortt sW[96*64];
    __shared__ float redS[24], redQ[24];
    __shared__ float ssl[48];
    int t = threadIdx.x;
    int b = blockIdx.x >> 4, pg = blockIdx.x & 15;
    int lane = t & 63, wid = t >> 6;
    int m = lane & 15, q4 = lane >> 4;
    if (t < 24) {
        redS[t] = 0.f; redQ[t] = 0.f;
        float s = mc2[((size_t)b*24 + t)*2], q = mc2[((size_t)b*24 + t)*2 + 1];
        float mean = s * (1.f/PL2);
        float var  = q * (1.f/PL2) - mean*mean;
        float rstd = rsqrtf(var + 1e-5f);
        float sc = g2[t]*rstd;
        ssl[t*2] = sc; ssl[t*2+1] = be2[t] - mean*sc;
    }
    // zero W pad block (logical g=3) per row; data goes to logical 0..2.
    if (t < 96) {
        uint4 z = {0,0,0,0};
        *(uint4*)&sW[t*64 + (((3 ^ (t & 3)) + (t & 4)) << 3)] = z;
    }
    // stage W (division-free): 2304 elems = 24c x 96n, padded to 24 x 128
    #pragma unroll
    for (int j = 0; j < 12; ++j) {
        int i = j*256 + t;                  // < 3072
        int c = i >> 7, n = i & 127;
        if (n < 96)
            sW[n*64 + (((((c >> 3) ^ (n & 3)) + (n & 4)) << 3) | (c & 7))] =
                (ushortt)bfbits(k3[c*96 + n]);
    }
    __syncthreads();
    // MFMA: wave = 32 px x 96 n, single K=32 step; A built in registers.
    b8v wv[6];
    #pragma unroll
    for (int nt = 0; nt < 6; ++nt) {
        int n = nt*16 + m;
        wv[nt] = *(const b8v*)&sW[n*64 + (((q4 ^ (n & 3)) + (n & 4)) << 3)];
    }
    f4v acc[2][6] = {};
    #pragma unroll
    for (int mt = 0; mt < 2; ++mt) {
        int px = wid*32 + mt*16 + m;
        int pix = pg*128 + px;
        int h4 = pix >> 6, w4 = pix & 63;
        const bf* base = c2 + (size_t)b*24*PL2 + (size_t)(2*h4)*W2 + 2*w4;
        uint4 au = {0,0,0,0};
        if (q4 < 3) {
            unsigned pr[4];
            #pragma unroll
            for (int jj = 0; jj < 4; ++jj) {
                unsigned two[2];
                #pragma unroll
                for (int cc = 0; cc < 2; ++cc) {
                    int c = q4*8 + jj*2 + cc;
                    const bf* pp = base + (size_t)c*PL2;
                    unsigned r0 = *(const unsigned*)pp;
                    unsigned r1 = *(const unsigned*)(pp + W2);
                    float sc = ssl[c*2], sh = ssl[c*2+1];
                    float e0 = fmaxf(b2f(r0 & 0xffff)*sc+sh, 0.f);
                    float e1 = fmaxf(b2f(r0 >> 16)   *sc+sh, 0.f);
                    float e2 = fmaxf(b2f(r1 & 0xffff)*sc+sh, 0.f);
                    float e3 = fmaxf(b2f(r1 >> 16)   *sc+sh, 0.f);
                    float mm = fmaxf(fmaxf(e0,e1), fmaxf(e2,e3));
                    mm = mm / (1.f + __expf(-mm));
                    two[cc] = bfbits(mm);
                }
                pr[jj] = two[0] | (two[1] << 16);
            }
            au.x = pr[0]; au.y = pr[1]; au.z = pr[2]; au.w = pr[3];
        }
        b8v av = __builtin_bit_cast(b8v, au);
        #pragma unroll
        for (int nt = 0; nt < 6; ++nt)
            acc[mt][nt] = __builtin_amdgcn_mfma_f32_16x16x32_bf16(av, wv[nt], acc[mt][nt], 0, 0, 0);
    }
    // Epilogue: lane-paired direct global uint4 stores + register stats.
    float sAcc[6] = {}, qAcc[6] = {};
    int qq = m & 1;
    #pragma unroll
    for (int nt = 0; nt < 6; ++nt) {
        int n = nt*16 + m;
        int o = n >> 2, d = (n >> 1) & 1;
        float bo = b3[o];
        #pragma unroll
        for (int mt = 0; mt < 2; ++mt) {
            int pxb = wid*32 + mt*16 + q4*4;
            unsigned wds[4];
            float s = 0.f, q = 0.f;
            #pragma unroll
            for (int r = 0; r < 4; ++r) {
                float v = acc[mt][nt][r] + bo;
                float vp = __shfl_xor(v, 1);
                unsigned lo = bfbits(v), hi = bfbits(vp);
                wds[r] = lo | (hi << 16);
                float f0 = b2f(lo), f1 = b2f(hi);
                s += f0 + f1;
                q += f0*f0 + f1*f1;
            }
            if (qq == 0) {
                int pix = pg*128 + pxb;
                int h4 = pix >> 6;
                int w4 = pix & 63;
                uint4 pk; pk.x = wds[0]; pk.y = wds[1]; pk.z = wds[2]; pk.w = wds[3];
                *(uint4*)(u3 + ((size_t)(b*24 + o))*PL2 + (size_t)(2*h4 + d)*W2 + 2*w4) = pk;
                sAcc[nt] += s; qAcc[nt] += q;
            }
        }
    }
    #pragma unroll
    for (int nt = 0; nt < 6; ++nt) {
        float s = sAcc[nt], q = qAcc[nt];
        s += __shfl_xor(s, 2);  q += __shfl_xor(q, 2);
        s += __shfl_xor(s, 16); q += __shfl_xor(q, 16);
        s += __shfl_xor(s, 32); q += __shfl_xor(q, 32);
        if ((lane & 51) == 0) {            // m&3==0 && q4==0
            int o = nt*4 + (m >> 2);
            atomicAdd(&redS[o], s);
            atomicAdd(&redQ[o], q);
        }
    }
    __syncthreads();
    if (t < 24) {
        atomicAdd(&mu3[((size_t)b*24 + t)*2],     redS[t]);
        atomicAdd(&mu3[((size_t)b*24 + t)*2 + 1], redQ[t]);
    }
}

// ---------------------------------------------------------------------------
// K10: gn3-fused tconv4 2x2 s2, 48->12 via MFMA. VECTOR-STAGED A:
// 6x uint4 coalesced loads/thread (8px x 1ch, gn3-affine applied) -> LDS
// sA2[48][256] channel-major, block-XOR swizzle pos = seg ^ (((ch>>3)&3)<<1)
// -> conflict-free per-lane ds_read_u16 fragment build. Replaces 48 scalar
// VMEM gathers/thread (25M VMEM instrs ~= 41 us of TA issue) with 3.1M.
// 2048 blocks.
__global__ __launch_bounds__(256) void k_tconv4(
    const bf* __restrict__ c2, const bf* __restrict__ u3,
    const float* __restrict__ mc2, const float* __restrict__ mu3,
    const float* __restrict__ g3, const float* __restrict__ be3,
    const float* __restrict__ k4, const float* __restrict__ bias4,
    bf* __restrict__ u4, float* __restrict__ mu4)
{
    __shared__ ushortt sW[48*64];               // [n][kb^(n&7) blocks of 8]
    __shared__ __align__(16) ushortt sA2[48*256]; // [ch][swizzled px blocks]
    __shared__ float redS[12], redQ[12];
    __shared__ float ssl[96];
    int t = threadIdx.x;
    int b = blockIdx.x >> 5, pg = blockIdx.x & 31;
    int lane = t & 63, wid = t >> 6;
    int m = lane & 15, q4 = lane >> 4;
    if (t < 12) { redS[t] = 0.f; redQ[t] = 0.f; }
    if (t < 6) {
        float s = 0.f, q = 0.f;
        #pragma unroll
        for (int cl = 0; cl < 8; ++cl) {
            int gc = t*8 + cl;
            const float* p = (gc < 24) ? mc2 + ((size_t)b*24 + gc)*2
                                       : mu3 + ((size_t)b*24 + gc - 24)*2;
            s += p[0]; q += p[1];
        }
        float inv_n = 1.f/((float)PL2*8.f);
        float mean = s*inv_n;
        float var  = q*inv_n - mean*mean;
        float rstd = rsqrtf(var + 1e-5f);
        #pragma unroll
        for (int cl = 0; cl < 8; ++cl) {
            int gc = t*8 + cl;
            float sc = g3[gc]*rstd;
            ssl[gc*2] = sc; ssl[gc*2+1] = be3[gc] - mean*sc;
        }
    }
    // stage W (division-free): 2304 = 48c x 48n, padded to 48 x 64
    #pragma unroll
    for (int j = 0; j < 12; ++j) {
        int i = j*256 + t;                 // < 3072
        int c = i >> 6, n = i & 63;
        if (n < 48)
            sW[n*64 + ((((c >> 3) ^ (n & 7)) << 3) | (c & 7))] =
                (ushortt)bfbits(k4[c*48 + n]);
    }
    if (t < 96) {                          // zero pad blocks kb=6,7
        uint4 z = {0,0,0,0};
        int n = t >> 1, kb = 6 + (t & 1);
        *(uint4*)&sW[n*64 + ((kb ^ (n & 7)) << 3)] = z;
    }
    __syncthreads();                       // ssl ready for affine staging
    // vector-stage A: 1536 uint4 = 48ch x 32 segs of 8px; 6 per thread.
    #pragma unroll
    for (int j = 0; j < 6; ++j) {
        int idx = j*256 + t;
        int ch = idx >> 5, seg = idx & 31;
        const bf* src = (ch < 24)
            ? c2 + (size_t)(b*24 + ch)*PL2 + pg*256 + seg*8
            : u3 + (size_t)(b*24 + ch - 24)*PL2 + pg*256 + seg*8;
        uint4 r = *(const uint4*)src;
        float sc = ssl[2*ch], sh = ssl[2*ch+1];
        uint4 pk;
        pk.x = bfbits(b2f(r.x & 0xffff)*sc+sh) | (bfbits(b2f(r.x >> 16)*sc+sh) << 16);
        pk.y = bfbits(b2f(r.y & 0xffff)*sc+sh) | (bfbits(b2f(r.y >> 16)*sc+sh) << 16);
        pk.z = bfbits(b2f(r.z & 0xffff)*sc+sh) | (bfbits(b2f(r.z >> 16)*sc+sh) << 16);
        pk.w = bfbits(b2f(r.w & 0xffff)*sc+sh) | (bfbits(b2f(r.w >> 16)*sc+sh) << 16);
        int sw = ((ch >> 3) & 3) << 1;
        *(uint4*)&sA2[ch*256 + ((seg ^ sw) << 3)] = pk;
    }
    __syncthreads();
    // MFMA: wave = 64 px x 48 n, K=64; fragments from sA2 (conflict-free).
    b8v bfr[3][2];
    #pragma unroll
    for (int nt = 0; nt < 3; ++nt) {
        int n = nt*16 + m;
        #pragma unroll
        for (int ks = 0; ks < 2; ++ks)
            bfr[nt][ks] = *(const b8v*)&sW[n*64 + (((ks*4 + q4) ^ (n & 7)) << 3)];
    }
    int swa = q4 << 1;                     // = ((ch>>3)&3)<<1 for both a0,a1
    f4v acc[4][3] = {};
    #pragma unroll
    for (int mt = 0; mt < 4; ++mt) {
        int px = wid*64 + mt*16 + m;
        int pb = px >> 3, po = px & 7;
        int badd = (((pb ^ swa) << 3) | po);
        unsigned pr[4];
        #pragma unroll
        for (int jj = 0; jj < 4; ++jj) {
            unsigned lo = sA2[(q4*8 + jj*2    )*256 + badd];
            unsigned hi = sA2[(q4*8 + jj*2 + 1)*256 + badd];
            pr[jj] = lo | (hi << 16);
        }
        uint4 u0; u0.x = pr[0]; u0.y = pr[1]; u0.z = pr[2]; u0.w = pr[3];
        b8v a0 = __builtin_bit_cast(b8v, u0);
        uint4 u1 = {0,0,0,0};
        if (q4 < 2) {
            unsigned pr1[4];
            #pragma unroll
            for (int jj = 0; jj < 4; ++jj) {
                unsigned lo = sA2[(32 + q4*8 + jj*2    )*256 + badd];
                unsigned hi = sA2[(32 + q4*8 + jj*2 + 1)*256 + badd];
                pr1[jj] = lo | (hi << 16);
            }
            u1.x = pr1[0]; u1.y = pr1[1]; u1.z = pr1[2]; u1.w = pr1[3];
        }
        b8v a1 = __builtin_bit_cast(b8v, u1);
        #pragma unroll
        for (int nt = 0; nt < 3; ++nt) {
            acc[mt][nt] = __builtin_amdgcn_mfma_f32_16x16x32_bf16(a0, bfr[nt][0], acc[mt][nt], 0, 0, 0);
            acc[mt][nt] = __builtin_amdgcn_mfma_f32_16x16x32_bf16(a1, bfr[nt][1], acc[mt][nt], 0, 0, 0);
        }
    }
    // Epilogue: lane-paired direct global uint4 stores + register stats.
    float sAcc[3] = {0.f, 0.f, 0.f}, qAcc[3] = {0.f, 0.f, 0.f};
    int qq = m & 1;
    #pragma unroll
    for (int nt = 0; nt < 3; ++nt) {
        int n = nt*16 + m;
        int o = n >> 2, d = (n >> 1) & 1;
        float bo = bias4[o];
        #pragma unroll
        for (int mt = 0; mt < 4; ++mt) {
            int pxb = wid*64 + mt*16 + q4*4;
            unsigned wds[4];
            float s = 0.f, q = 0.f;
            #pragma unroll
            for (int r = 0; r < 4; ++r) {
                float v = acc[mt][nt][r] + bo;
                float vp = __shfl_xor(v, 1);
                unsigned lo = bfbits(v), hi = bfbits(vp);
                wds[r] = lo | (hi << 16);
                float f0 = b2f(lo), f1 = b2f(hi);
                s += f0 + f1;
                q += f0*f0 + f1*f1;
            }
            if (qq == 0) {
                int h2 = (pg*256 + pxb) >> 7;
                int w0 = pxb & 127;
                uint4 pk; pk.x = wds[0]; pk.y = wds[1]; pk.z = wds[2]; pk.w = wds[3];
                *(uint4*)(u4 + (((size_t)(b*12 + o))*HH + 2*h2 + d)*EE + 2*w0) = pk;
                sAcc[nt] += s; qAcc[nt] += q;
            }
        }
    }
    #pragma unroll
    for (int nt = 0; nt < 3; ++nt) {
        float s = sAcc[nt], q = qAcc[nt];
        s += __shfl_xor(s, 2);  q += __shfl_xor(q, 2);
        s += __shfl_xor(s, 16); q += __shfl_xor(q, 16);
        s += __shfl_xor(s, 32); q += __shfl_xor(q, 32);
        if ((lane & 51) == 0) {
            int o = nt*4 + (m >> 2);
            atomicAdd(&redS[o], s);
            atomicAdd(&redQ[o], q);
        }
    }
    __syncthreads();
    if (t < 12) {
        atomicAdd(&mu4[((size_t)b*12 + t)*2],     redS[t]);
        atomicAdd(&mu4[((size_t)b*12 + t)*2 + 1], redQ[t]);
    }
}

// ---------------------------------------------------------------------------
// K12: gn4-fused 1x1 conv 18->6. gn4 prologue from mc1+mu4. 8 px/thread,
// uint4 loads/stores. Fused u5 stats. 1024 blocks.
__global__ __launch_bounds__(256) void k_conv1x1_u5(
    const bf* __restrict__ c1, const bf* __restrict__ u4,
    const float* __restrict__ mc1, const float* __restrict__ mu4,
    const float* __restrict__ g4, const float* __restrict__ be4,
    const float* __restrict__ k, const float* __restrict__ bias,
    bf* __restrict__ u5, float* __restrict__ mu5)
{
    __shared__ float red[4][6][2];
    __shared__ float ssl[36];
    int t = threadIdx.x;
    int b  = blockIdx.x >> 4;
    int pg = blockIdx.x & 15;
    int pix = pg*2048 + t*8;
    int lane = t & 63, wid = t >> 6;
    if (t < 6) {
        float s = 0.f, q = 0.f;
        #pragma unroll
        for (int cl = 0; cl < 3; ++cl) {
            int gc = t*3 + cl;
            const float* p = (gc < 6) ? mc1 + ((size_t)b*6 + gc)*2
                                      : mu4 + ((size_t)b*12 + gc - 6)*2;
            s += p[0]; q += p[1];
        }
        float inv_n = 1.f/((float)HP*3.f);
        float mean = s*inv_n;
        float var  = q*inv_n - mean*mean;
        float rstd = rsqrtf(var + 1e-5f);
        #pragma unroll
        for (int cl = 0; cl < 3; ++cl) {
            int gc = t*3 + cl;
            float sc = g4[gc]*rstd;
            ssl[gc*2] = sc; ssl[gc*2+1] = be4[gc] - mean*sc;
        }
    }
    __syncthreads();
    const bf* c1p = c1 + ((size_t)b*6)*HP + pix;
    const bf* u4p = u4 + ((size_t)b*12)*HP + pix;
    float acc[6][8];
    #pragma unroll
    for (int o = 0; o < 6; ++o) {
        float bv = bias[o];
        #pragma unroll
        for (int j = 0; j < 8; ++j) acc[o][j] = bv;
    }
    #pragma unroll
    for (int c = 0; c < 18; ++c) {
        uint4 r = (c < 6) ? *(const uint4*)(c1p + (size_t)c*HP)
                          : *(const uint4*)(u4p + (size_t)(c-6)*HP);
        float sc = ssl[2*c], sh = ssl[2*c+1];
        float v[8];
        v[0] = b2f(r.x & 0xffff)*sc + sh;  v[1] = b2f(r.x >> 16)*sc + sh;
        v[2] = b2f(r.y & 0xffff)*sc + sh;  v[3] = b2f(r.y >> 16)*sc + sh;
        v[4] = b2f(r.z & 0xffff)*sc + sh;  v[5] = b2f(r.z >> 16)*sc + sh;
        v[6] = b2f(r.w & 0xffff)*sc + sh;  v[7] = b2f(r.w >> 16)*sc + sh;
        #pragma unroll
        for (int o = 0; o < 6; ++o) {
            float wv = k[o*18 + c];
            #pragma unroll
            for (int j = 0; j < 8; ++j) acc[o][j] += v[j]*wv;
        }
    }
    #pragma unroll
    for (int o = 0; o < 6; ++o) {
        uint4 pk;
        pk.x = bfbits(acc[o][0]) | (bfbits(acc[o][1]) << 16);
        pk.y = bfbits(acc[o][2]) | (bfbits(acc[o][3]) << 16);
        pk.z = bfbits(acc[o][4]) | (bfbits(acc[o][5]) << 16);
        pk.w = bfbits(acc[o][6]) | (bfbits(acc[o][7]) << 16);
        *(uint4*)(u5 + ((size_t)(b*6+o))*HP + pix) = pk;
        float s = 0.f, q = 0.f;
        #pragma unroll
        for (int j = 0; j < 8; ++j) { s += acc[o][j]; q += acc[o][j]*acc[o][j]; }
        wred2(s, q);
        if (lane == 0) { red[wid][o][0] = s; red[wid][o][1] = q; }
    }
    __syncthreads();
    if (t < 6) {
        float S = 0.f, Q = 0.f;
        #pragma unroll
        for (int wv = 0; wv < 4; ++wv) { S += red[wv][t][0]; Q += red[wv][t][1]; }
        atomicAdd(&mu5[((size_t)b*6 + t)*2],     S);
        atomicAdd(&mu5[((size_t)b*6 + t)*2 + 1], Q);
    }
}

// ---------------------------------------------------------------------------
// K14: gn5-fused final 1x1 conv (6->1) + divide by std(t). gn5 in prologue.
// 8 px/thread, uint4 loads, 2x float4 stores. 1024 blocks.
__global__ __launch_bounds__(256) void k_final(
    const bf* __restrict__ u5, const float* __restrict__ mu5,
    const float* __restrict__ g5, const float* __restrict__ be5,
    const float* __restrict__ k, const float* __restrict__ bias,
    const float* __restrict__ t, float* __restrict__ out)
{
    __shared__ float ssl[12];
    int tt = threadIdx.x;
    int b = blockIdx.x >> 4;
    int pix = ((blockIdx.x & 15)*256 + tt)*8;
    if (tt < 6) {
        float s = mu5[((size_t)b*6 + tt)*2], q = mu5[((size_t)b*6 + tt)*2 + 1];
        float mean = s * (1.f/HP);
        float var  = q * (1.f/HP) - mean*mean;
        float rstd = rsqrtf(var + 1e-5f);
        float sc = g5[tt]*rstd;
        ssl[tt*2] = sc; ssl[tt*2+1] = be5[tt] - mean*sc;
    }
    __syncthreads();
    const bf* up = u5 + (size_t)b*6*HP + pix;
    float bv = bias[0];
    float a[8];
    #pragma unroll
    for (int j = 0; j < 8; ++j) a[j] = bv;
    #pragma unroll
    for (int c = 0; c < 6; ++c) {
        uint4 r = *(const uint4*)(up + (size_t)c*HP);
        float sc = ssl[2*c], sh = ssl[2*c+1];
        float wv = k[c];
        a[0] += (b2f(r.x & 0xffff)*sc + sh) * wv;
        a[1] += (b2f(r.x >> 16)   *sc + sh) * wv;
        a[2] += (b2f(r.y & 0xffff)*sc + sh) * wv;
        a[3] += (b2f(r.y >> 16)   *sc + sh) * wv;
        a[4] += (b2f(r.z & 0xffff)*sc + sh) * wv;
        a[5] += (b2f(r.z >> 16)   *sc + sh) * wv;
        a[6] += (b2f(r.w & 0xffff)*sc + sh) * wv;
        a[7] += (b2f(r.w >> 16)   *sc + sh) * wv;
    }
    float tb = t[b];
    const float lns = 3.2188758248682007492f;
    float var = (__expf(2.f*tb*lns) - 1.f) / (2.f*lns);
    float rs = rsqrtf(var);
    float4 o0; o0.x = a[0]*rs; o0.y = a[1]*rs; o0.z = a[2]*rs; o0.w = a[3]*rs;
    float4 o1; o1.x = a[4]*rs; o1.y = a[5]*rs; o1.z = a[6]*rs; o1.w = a[7]*rs;
    float* op = out + (size_t)b*HP + pix;
    *(float4*)op       = o0;
    *(float4*)(op + 4) = o1;
}

// ---------------------------------------------------------------------------
extern "C" void kernel_launch(void* const* d_in, const int* in_sizes, int n_in,
                              void* d_out, int out_size, void* d_ws, size_t ws_size,
                              hipStream_t stream)
{
    const float* x       = (const float*)d_in[0];
    const float* t       = (const float*)d_in[1];
    const float* Wf      = (const float*)d_in[2];
    const float* fc1_w   = (const float*)d_in[3];
    const float* fc1_b   = (const float*)d_in[4];
    const float* conv1_k = (const float*)d_in[5];
    const float* conv1_b = (const float*)d_in[6];
    const float* gn1_g   = (const float*)d_in[7];
    const float* gn1_b   = (const float*)d_in[8];
    const float* conv2_k = (const float*)d_in[9];
    const float* conv2_b = (const float*)d_in[10];
    const float* gn2_g   = (const float*)d_in[11];
    const float* gn2_b   = (const float*)d_in[12];
    const float* t3_k    = (const float*)d_in[13];
    const float* t3_b    = (const float*)d_in[14];
    const float* gn3_g   = (const float*)d_in[15];
    const float* gn3_b   = (const float*)d_in[16];
    const float* t4_k    = (const float*)d_in[17];
    const float* t4_b    = (const float*)d_in[18];
    const float* gn4_g   = (const float*)d_in[19];
    const float* gn4_b   = (const float*)d_in[20];
    const float* t5_k    = (const float*)d_in[21];
    const float* t5_b    = (const float*)d_in[22];
    const float* gn5_g   = (const float*)d_in[23];
    const float* gn5_b   = (const float*)d_in[24];
    const float* fin_k   = (const float*)d_in[25];
    const float* fin_b   = (const float*)d_in[26];

    bf* wsb = (bf*)d_ws;
    bf* c1 = wsb;                          // conv1..conv1x1
    bf* c2 = wsb + 12582912;               // conv2..tconv4
    bf* u3 = wsb + 25165824;               // tconv3..tconv4
    bf* u4 = wsb + 37748736;               // tconv4..conv1x1
    bf* xf = wsb + 39845888;               // fc1..conv1 (in u4 region)
    bf* u5 = wsb + 12582912;               // reuses c2, conv1x1..final
    float* mb = (float*)(wsb + 62914560);  // raw channel sums
    float* mc1 = mb;            // 768
    float* mc2 = mb + 768;      // 3072
    float* mu3 = mb + 3840;     // 3072
    float* mu4 = mb + 6912;     // 1536
    float* mu5 = mb + 8448;     // 768

    k_fourier_fc1<<<512, 256, 0, stream>>>(x, Wf, fc1_w, fc1_b, xf, mb);
    k_conv1<<<2048, 256, 0, stream>>>(xf, conv1_k, conv1_b, c1, mc1);
    k_conv2<<<1024, 256, 0, stream>>>(c1, mc1, gn1_g, gn1_b,
                                      conv2_k, conv2_b, c2, mc2);
    k_tconv3<<<1024, 256, 0, stream>>>(c2, mc2, gn2_g, gn2_b,
                                       t3_k, t3_b, u3, mu3);
    k_tconv4<<<2048, 256, 0, stream>>>(c2, u3, mc2, mu3, gn3_g, gn3_b,
                                       t4_k, t4_b, u4, mu4);
    k_conv1x1_u5<<<1024, 256, 0, stream>>>(c1, u4, mc1, mu4, gn4_g, gn4_b,
                                           t5_k, t5_b, u5, mu5);
    k_final<<<1024, 256, 0, stream>>>(u5, mu5, gn5_g, gn5_b,
                                      fin_k, fin_b, t, (float*)d_out);
}